// Round 10
// baseline (169.441 us; speedup 1.0000x reference)
//
#include <hip/hip_runtime.h>

#define NS 256
#define NW 128
#define NH 768
#define NL 384          // TOPK*W keys
#define WH (NW*NH)      // 98304
#define OUTROWS 127

typedef __attribute__((ext_vector_type(8))) short short8;
typedef __attribute__((ext_vector_type(8))) unsigned short ushort8;
typedef __attribute__((ext_vector_type(8))) __bf16 bf16x8;
typedef __attribute__((ext_vector_type(4))) float f32x4;

#define XS_STRIDE 72          // QK staging [384][72] bf16 (144B rows -> 2-way max, free)
#define PS_STRIDE 392         // Ps [64][392] bf16, XOR-swizzled rows
#define VT_STRIDE 392         // VT [32][392] bf16, XOR-swizzled
#define OFF_VT   50176        // Ps: [0, 50176); VT: [50176, 75264)
#define OFF_RED1 75264        // [64][8] f32
#define OFF_RED2 77312        // [64][8] f32
#define SMEM_TOTAL 79360      // x2 blocks/CU = 158720 <= 163840

__device__ __forceinline__ unsigned short bf16b(float f) {   // sw RNE (cold path)
  union { float f; unsigned u; } x; x.f = f;
  return (unsigned short)((x.u + 0x7fffu + ((x.u >> 16) & 1u)) >> 16);
}
__device__ __forceinline__ float b2f(unsigned short h) {
  union { unsigned u; float f; } x; x.u = ((unsigned)h) << 16;
  return x.f;
}
__device__ __forceinline__ unsigned short bfc(float f) {     // hw cvt (RNE)
  __bf16 h = (__bf16)f;
  return __builtin_bit_cast(unsigned short, h);
}

// ---- prelude, ONE launch: top3 (blk 0..255) + PE table (256..543) + bf16 precast (544..3615) ----
__global__ __launch_bounds__(1024) void k_pre(const float* __restrict__ inp,
                                              int* __restrict__ idxw,
                                              unsigned short* __restrict__ peb,
                                              unsigned short* __restrict__ inpb) {
  const int t = threadIdx.x;
  const int b = blockIdx.x;
  if (b >= 544) {               // bf16 precast: 3072 blocks x 8192 elems
    size_t base = ((size_t)(b - 544) * 1024 + t) * 8;
    float4 a = *(const float4*)(inp + base);
    float4 c = *(const float4*)(inp + base + 4);
    ushort8 o;
    o[0] = bfc(a.x); o[1] = bfc(a.y); o[2] = bfc(a.z); o[3] = bfc(a.w);
    o[4] = bfc(c.x); o[5] = bfc(c.y); o[6] = bfc(c.z); o[7] = bfc(c.w);
    *(ushort8*)(inpb + base) = o;
    return;
  }
  if (b >= NS) {                // PE table: 288 blocks cover 384*768
    int gid = (b - NS) * 1024 + t;
    int l = gid / NH, d = gid - l * NH;
    const float c = -0.011992630687355995f;      // (float)(-log(1e4)/768)
    float dv = __expf((float)(d & ~1) * c);
    float ang = (float)l * dv;
    float v = (d & 1) ? cosf(ang) : sinf(ang);
    peb[gid] = bf16b(v);
    return;
  }
  const int i = b;              // top-3 NN (stable, smallest-index ties)
  __shared__ float xi[772];                   // 4 segs of 193 (192 + 1 pad)
  __shared__ float dist[NS];
  __shared__ unsigned long long wkeys[16];
  for (int h = t; h < NH; h += 1024) xi[h + h / 192] = inp[(size_t)i * WH + h];
  __syncthreads();
  const int c = t >> 2, seg = t & 3;
  const float* __restrict__ row = inp + (size_t)c * WH + seg * 192;
  const float* xis = xi + seg * 193;
  float s = 0.f;
  #pragma unroll 4
  for (int h = 0; h < 192; h += 4) {
    float4 v = *(const float4*)(row + h);
    s += fabsf(xis[h]     - v.x) + fabsf(xis[h + 1] - v.y)
       + fabsf(xis[h + 2] - v.z) + fabsf(xis[h + 3] - v.w);
  }
  s += __shfl_xor(s, 1, 64);
  s += __shfl_xor(s, 2, 64);
  if (seg == 0) dist[c] = s;
  __syncthreads();
  for (int k = 0; k < 3; ++k) {
    float d = (t < NS) ? dist[t] : 3.4e38f;
    unsigned long long key = ((unsigned long long)__float_as_uint(d) << 32) | (unsigned)t;
    #pragma unroll
    for (int dd = 1; dd < 64; dd <<= 1) {
      unsigned long long o = __shfl_xor(key, dd, 64);
      key = (o < key) ? o : key;
    }
    if ((t & 63) == 0) wkeys[t >> 6] = key;
    __syncthreads();
    if (t == 0) {
      unsigned long long best = wkeys[0];
      for (int w = 1; w < 16; ++w) if (wkeys[w] < best) best = wkeys[w];
      int bj = (int)(best & 0xffffffffu);
      idxw[i * 3 + k] = bj;
      dist[bj] = 3.4e38f;
    }
    __syncthreads();
  }
}

// ---- fused attention: TWO blocks per s (64 q-rows each), 8 waves, 2 blocks/CU ----
// LDS 79.4KB/block -> 2 blocks/CU = 4 waves/SIMD -> VGPR tier 128. PIN IT: the
// allocator's own tier pick is unreliable (r9: chose 64, spilled; r3/r4/r6 same story).
__global__ __launch_bounds__(512, 4)
void k_attn(const unsigned short* __restrict__ inpb, const unsigned short* __restrict__ peb,
            const int* __restrict__ idxw, float* __restrict__ out) {
  extern __shared__ char smem[];
  unsigned short* Xs = (unsigned short*)smem;              // QK: [384][72] (55.3KB)
  unsigned short* Ps = (unsigned short*)smem;              // PV: [64][392] (50.2KB, after QK)
  unsigned short* VT = (unsigned short*)(smem + OFF_VT);   // PV: [32][392] (24.5KB)
  float* red1 = (float*)(smem + OFF_RED1);                 // [64][8]
  float* red2 = (float*)(smem + OFF_RED2);                 // [64][8]

  const int s  = blockIdx.x >> 1;
  const int qh = blockIdx.x & 1;           // q-half: rows qh*64 .. qh*64+63
  const int tid = threadIdx.x;
  const int lane = tid & 63, wid = tid >> 6;
  const int lrow = lane & 15, lhi = lane >> 4;
  const int i0 = idxw[s * 3 + 0], i1 = idxw[s * 3 + 1], i2 = idxw[s * 3 + 2];

  const f32x4 fz = {0.f, 0.f, 0.f, 0.f};
  f32x4 acc[4][3];                          // 64q x 48k per wave (k = wid*48 ..)
  #pragma unroll
  for (int qs = 0; qs < 4; ++qs)
    #pragma unroll
    for (int kf = 0; kf < 3; ++kf) acc[qs][kf] = fz;

  const int rl0 = tid >> 3, c8 = (tid & 7) * 8;

  // ============ QK^T: 12 h-chunks of 64 ============
  for (int hc = 0; hc < 12; ++hc) {
    const int h0 = hc * 64;
    #pragma unroll
    for (int it = 0; it < 6; ++it) {
      const int src = (it < 2) ? i0 : (it < 4 ? i1 : i2);
      const int rl = rl0 + (it & 1) * 64;                   // 0..127 within source
      const int r  = rl + (it >> 1) * 128;                  // fused row 0..383
      ushort8 xv = *(const ushort8*)&inpb[(size_t)src * WH + (size_t)rl * NH + h0 + c8];
      ushort8 pv = *(const ushort8*)&peb[r * NH + h0 + c8];
      bf16x8 o;
      #pragma unroll
      for (int j = 0; j < 8; ++j) o[j] = (__bf16)(b2f(xv[j]) + b2f(pv[j]));
      *reinterpret_cast<bf16x8*>(&Xs[r * XS_STRIDE + c8]) = o;
    }
    __syncthreads();
    __builtin_amdgcn_s_setprio(1);
    #pragma unroll
    for (int ks = 0; ks < 64; ks += 32) {
      short8 a[4];
      #pragma unroll
      for (int qs = 0; qs < 4; ++qs)
        a[qs] = *reinterpret_cast<const short8*>(
            &Xs[(qh * 64 + qs * 16 + lrow) * XS_STRIDE + ks + lhi * 8]);
      #pragma unroll
      for (int kf = 0; kf < 3; ++kf) {
        short8 b = *reinterpret_cast<const short8*>(
            &Xs[(wid * 48 + kf * 16 + lrow) * XS_STRIDE + ks + lhi * 8]);
        #pragma unroll
        for (int qs = 0; qs < 4; ++qs)
          acc[qs][kf] = __builtin_amdgcn_mfma_f32_16x16x32_bf16(a[qs], b, acc[qs][kf], 0, 0, 0);
      }
    }
    __builtin_amdgcn_s_setprio(0);
    __syncthreads();
  }

  // ============ softmax (64 rows; k split across 8 waves; red [64][8]) ============
  const float scale = 0.03608439182435161f;  // 1/sqrt(768)
  float mx[4][4];
  #pragma unroll
  for (int qs = 0; qs < 4; ++qs)
    #pragma unroll
    for (int r = 0; r < 4; ++r) {
      float m = fmaxf(fmaxf(acc[qs][0][r], acc[qs][1][r]), acc[qs][2][r]);
      #pragma unroll
      for (int d = 1; d < 16; d <<= 1) m = fmaxf(m, __shfl_xor(m, d, 64));
      mx[qs][r] = m;
    }
  if (lrow == 0) {
    #pragma unroll
    for (int qs = 0; qs < 4; ++qs)
      #pragma unroll
      for (int r = 0; r < 4; ++r)
        red1[(qs * 16 + lhi * 4 + r) * 8 + wid] = mx[qs][r];
  }
  __syncthreads();
  float sm[4][4];
  #pragma unroll
  for (int qs = 0; qs < 4; ++qs)
    #pragma unroll
    for (int r = 0; r < 4; ++r) {
      const int row = qs * 16 + lhi * 4 + r;
      float4 m0 = *(const float4*)&red1[row * 8];
      float4 m1 = *(const float4*)&red1[row * 8 + 4];
      mx[qs][r] = fmaxf(fmaxf(fmaxf(m0.x, m0.y), fmaxf(m0.z, m0.w)),
                        fmaxf(fmaxf(m1.x, m1.y), fmaxf(m1.z, m1.w)));
      sm[qs][r] = 0.f;
    }
  #pragma unroll
  for (int qs = 0; qs < 4; ++qs)
    #pragma unroll
    for (int kf = 0; kf < 3; ++kf)
      #pragma unroll
      for (int r = 0; r < 4; ++r) {
        float p = __expf((acc[qs][kf][r] - mx[qs][r]) * scale);
        acc[qs][kf][r] = p;
        sm[qs][r] += p;
      }
  #pragma unroll
  for (int qs = 0; qs < 4; ++qs)
    #pragma unroll
    for (int r = 0; r < 4; ++r) {
      #pragma unroll
      for (int d = 1; d < 16; d <<= 1) sm[qs][r] += __shfl_xor(sm[qs][r], d, 64);
    }
  if (lrow == 0) {
    #pragma unroll
    for (int qs = 0; qs < 4; ++qs)
      #pragma unroll
      for (int r = 0; r < 4; ++r)
        red2[(qs * 16 + lhi * 4 + r) * 8 + wid] = sm[qs][r];
  }
  __syncthreads();
  #pragma unroll
  for (int qs = 0; qs < 4; ++qs)
    #pragma unroll
    for (int r = 0; r < 4; ++r) {
      const int row = qs * 16 + lhi * 4 + r;
      float4 s0 = *(const float4*)&red2[row * 8];
      float4 s1 = *(const float4*)&red2[row * 8 + 4];
      sm[qs][r] = 1.0f / ((s0.x + s0.y) + (s0.z + s0.w) + (s1.x + s1.y) + (s1.z + s1.w));
    }
  // write normalized P (bf16) -> Ps[64][392] (overlays dead Xs), byte-XOR ((row>>3)&7)<<4
  #pragma unroll
  for (int qs = 0; qs < 4; ++qs)
    #pragma unroll
    for (int kf = 0; kf < 3; ++kf)
      #pragma unroll
      for (int r = 0; r < 4; ++r) {
        const int row = qs * 16 + lhi * 4 + r;
        const int col = wid * 48 + kf * 16 + lrow;
        *(unsigned short*)((char*)Ps + (((row * PS_STRIDE + col) * 2) ^ (((row >> 3) & 7) << 4))) =
            bfc(acc[qs][kf][r] * sm[qs][r]);
      }
  __syncthreads();

  // ============ PV: 24 phases of 32 h-cols; per wave 16q x 16h per phase ============
  const int qb = wid & 3, hsub = wid >> 2;
  short8 pa[12];
  #pragma unroll
  for (int m0 = 0; m0 < 12; ++m0) {
    const int row = qb * 16 + lrow;
    pa[m0] = *reinterpret_cast<const short8*>(
        (const char*)Ps + (((row * PS_STRIDE + m0 * 32 + lhi * 8) * 2) ^ (((row >> 3) & 7) << 4)));
  }
  const int mB  = (tid >> 2);              // 0..127: m within 128-slab
  const int vc8 = (tid & 3) * 8;           // 0,8,16,24
  const int q_out = qh * 64 + qb * 16 + lhi * 4;

  for (int t4 = 0; t4 < 24; ++t4) {
    const int h0 = t4 * 32;
    #pragma unroll
    for (int it = 0; it < 3; ++it) {
      const int src = (it == 0) ? i0 : (it == 1 ? i1 : i2);
      const int m = it * 128 + mB;         // fused row 0..383
      ushort8 xv = *(const ushort8*)&inpb[(size_t)src * WH + (size_t)mB * NH + h0 + vc8];
      ushort8 pv = *(const ushort8*)&peb[m * NH + h0 + vc8];
      #pragma unroll
      for (int j = 0; j < 8; ++j) {
        const int vr = vc8 + j;            // 0..31
        VT[((vr * VT_STRIDE) + m) ^ (((vr >> 3) & 3) << 4)] = bfc(b2f(xv[j]) + b2f(pv[j]));
      }
    }
    __syncthreads();
    __builtin_amdgcn_s_setprio(1);
    f32x4 o = fz;
    const int vr0 = hsub * 16 + lrow;
    const int swz = ((vr0 >> 3) & 3) << 5;   // byte XOR
    #pragma unroll
    for (int mm = 0; mm < 12; ++mm) {
      short8 b = *reinterpret_cast<const short8*>(
          (const char*)VT + ((vr0 * VT_STRIDE * 2 + (mm * 32 + lhi * 8) * 2) ^ swz));
      o = __builtin_amdgcn_mfma_f32_16x16x32_bf16(pa[mm], b, o, 0, 0, 0);
    }
    __builtin_amdgcn_s_setprio(0);
    const int h = h0 + hsub * 16 + lrow;
    float* ob = out + (size_t)s * (OUTROWS * NH) + h;
    #pragma unroll
    for (int r = 0; r < 4; ++r) {
      const int q = q_out + r;
      if (q < OUTROWS) ob[(size_t)q * NH] = o[r];
    }
    __syncthreads();
  }
}

// ---------------- launch ----------------
extern "C" void kernel_launch(void* const* d_in, const int* in_sizes, int n_in,
                              void* d_out, int out_size, void* d_ws, size_t ws_size,
                              hipStream_t stream) {
  (void)in_sizes; (void)n_in; (void)out_size; (void)ws_size;
  const float* inp = (const float*)d_in[0];
  float* out = (float*)d_out;
  char* ws = (char*)d_ws;

  unsigned short* peb = (unsigned short*)ws;                     // 589824 B
  int* idxw           = (int*)(ws + 589824);                     // 3072 B
  unsigned short* inpb= (unsigned short*)(ws + 592896);          // 50331648 B

  hipLaunchKernelGGL(k_pre, dim3(256 + 288 + 3072), dim3(1024), 0, stream,
                     inp, idxw, peb, inpb);

  hipFuncSetAttribute((const void*)k_attn,
                      hipFuncAttributeMaxDynamicSharedMemorySize, SMEM_TOTAL);
  hipLaunchKernelGGL(k_attn, dim3(512), dim3(512), SMEM_TOTAL, stream,
                     inpb, peb, idxw, out);
}

// Round 11
// 152.530 us; speedup vs baseline: 1.1109x; 1.1109x over previous
//
#include <hip/hip_runtime.h>

#define NS 256
#define NW 128
#define NH 768
#define NL 384          // TOPK*W keys
#define WH (NW*NH)      // 98304
#define OUTROWS 127

typedef __attribute__((ext_vector_type(8))) short short8;
typedef __attribute__((ext_vector_type(8))) unsigned short ushort8;
typedef __attribute__((ext_vector_type(8))) __bf16 bf16x8;
typedef __attribute__((ext_vector_type(4))) float f32x4;

#define XS2_STRIDE 136        // QK staging [384][136] bf16 (272B rows; r8-proven conflict-free)
#define PS_STRIDE 392         // Ps [128][392] bf16, XOR-swizzled rows
#define SMEM_PS   55296       // Ps offset; QK's 104KB Xs2 overlaps it (Ps written after QK)
#define SMEM_RED  (SMEM_PS + 128*PS_STRIDE*2)   // 155648
#define SMEM_TOTAL (SMEM_RED + 4096)            // 159744 <= 163840 (r8-proven size)

__device__ __forceinline__ unsigned short bf16b(float f) {   // sw RNE (cold path)
  union { float f; unsigned u; } x; x.f = f;
  return (unsigned short)((x.u + 0x7fffu + ((x.u >> 16) & 1u)) >> 16);
}
__device__ __forceinline__ float b2f(unsigned short h) {
  union { unsigned u; float f; } x; x.u = ((unsigned)h) << 16;
  return x.f;
}
__device__ __forceinline__ unsigned short bfc(float f) {     // hw cvt (RNE)
  __bf16 h = (__bf16)f;
  return __builtin_bit_cast(unsigned short, h);
}

// ---- prelude, ONE launch: top3 (blk 0..255) + PE table (256..543) + bf16 precast (544..3615) ----
__global__ __launch_bounds__(1024) void k_pre(const float* __restrict__ inp,
                                              int* __restrict__ idxw,
                                              unsigned short* __restrict__ peb,
                                              unsigned short* __restrict__ inpb) {
  const int t = threadIdx.x;
  const int b = blockIdx.x;
  if (b >= 544) {               // bf16 precast: 3072 blocks x 8192 elems
    size_t base = ((size_t)(b - 544) * 1024 + t) * 8;
    float4 a = *(const float4*)(inp + base);
    float4 c = *(const float4*)(inp + base + 4);
    ushort8 o;
    o[0] = bfc(a.x); o[1] = bfc(a.y); o[2] = bfc(a.z); o[3] = bfc(a.w);
    o[4] = bfc(c.x); o[5] = bfc(c.y); o[6] = bfc(c.z); o[7] = bfc(c.w);
    *(ushort8*)(inpb + base) = o;
    return;
  }
  if (b >= NS) {                // PE table: 288 blocks cover 384*768
    int gid = (b - NS) * 1024 + t;
    int l = gid / NH, d = gid - l * NH;
    const float c = -0.011992630687355995f;      // (float)(-log(1e4)/768)
    float dv = __expf((float)(d & ~1) * c);
    float ang = (float)l * dv;
    float v = (d & 1) ? cosf(ang) : sinf(ang);
    peb[gid] = bf16b(v);
    return;
  }
  const int i = b;              // top-3 NN (stable, smallest-index ties)
  __shared__ float xi[772];                   // 4 segs of 193 (192 + 1 pad)
  __shared__ float dist[NS];
  __shared__ unsigned long long wkeys[16];
  for (int h = t; h < NH; h += 1024) xi[h + h / 192] = inp[(size_t)i * WH + h];
  __syncthreads();
  const int c = t >> 2, seg = t & 3;
  const float* __restrict__ row = inp + (size_t)c * WH + seg * 192;
  const float* xis = xi + seg * 193;
  float s = 0.f;
  #pragma unroll 4
  for (int h = 0; h < 192; h += 4) {
    float4 v = *(const float4*)(row + h);
    s += fabsf(xis[h]     - v.x) + fabsf(xis[h + 1] - v.y)
       + fabsf(xis[h + 2] - v.z) + fabsf(xis[h + 3] - v.w);
  }
  s += __shfl_xor(s, 1, 64);
  s += __shfl_xor(s, 2, 64);
  if (seg == 0) dist[c] = s;
  __syncthreads();
  for (int k = 0; k < 3; ++k) {
    float d = (t < NS) ? dist[t] : 3.4e38f;
    unsigned long long key = ((unsigned long long)__float_as_uint(d) << 32) | (unsigned)t;
    #pragma unroll
    for (int dd = 1; dd < 64; dd <<= 1) {
      unsigned long long o = __shfl_xor(key, dd, 64);
      key = (o < key) ? o : key;
    }
    if ((t & 63) == 0) wkeys[t >> 6] = key;
    __syncthreads();
    if (t == 0) {
      unsigned long long best = wkeys[0];
      for (int w = 1; w < 16; ++w) if (wkeys[w] < best) best = wkeys[w];
      int bj = (int)(best & 0xffffffffu);
      idxw[i * 3 + k] = bj;
      dist[bj] = 3.4e38f;
    }
    __syncthreads();
  }
}

// ---- fused attention: ONE block per s, 16 waves (1024 thr), 4 waves/SIMD ----
// r8's traffic (one staging pass per s) + r9's occupancy. 1024-thr blocks are
// launch-capped at 128 VGPR; r9 proved this per-wave working set fits in 64+AGPR.
// waves_per_eu(4,4): allocator targets the only feasible occupancy (LDS -> 1 blk/CU).
__global__ __launch_bounds__(1024) __attribute__((amdgpu_waves_per_eu(4, 4)))
void k_attn(const unsigned short* __restrict__ inpb, const unsigned short* __restrict__ peb,
            const int* __restrict__ idxw, float* __restrict__ out) {
  extern __shared__ char smem[];
  unsigned short* Xs = (unsigned short*)smem;              // QK: [384][136] (104KB, overlaps Ps)
  unsigned short* VT = (unsigned short*)smem;              // PV: [64][392] (50.2KB)
  unsigned short* Ps = (unsigned short*)(smem + SMEM_PS);  // [128][392] bf16, swizzled
  float* red = (float*)(smem + SMEM_RED);                  // [128][8], reused max->sum

  const int s = blockIdx.x;
  const int tid = threadIdx.x;
  const int lane = tid & 63, wid = tid >> 6;               // 16 waves
  const int lrow = lane & 15, lhi = lane >> 4;
  const int i0 = idxw[s * 3 + 0], i1 = idxw[s * 3 + 1], i2 = idxw[s * 3 + 2];

  const f32x4 fz = {0.f, 0.f, 0.f, 0.f};
  f32x4 acc[4][3];                         // QK: wave (qh,kq) owns 64q x 48k
  #pragma unroll
  for (int qs = 0; qs < 4; ++qs)
    #pragma unroll
    for (int kf = 0; kf < 3; ++kf) acc[qs][kf] = fz;

  const int qh = wid & 1, kq = wid >> 1;   // qh: q-half (64), kq: k-slice (48)

  // ============ QK^T: 6 h-chunks of 128 ============
  for (int hc = 0; hc < 6; ++hc) {
    const int h0 = hc * 128;
    #pragma unroll
    for (int it = 0; it < 6; ++it) {       // 64 rows x 16 col-groups per it
      const int src = (it < 2) ? i0 : (it < 4 ? i1 : i2);
      const int rl = (it & 1) * 64 + (tid >> 4);           // row within slab
      const int r  = it * 64 + (tid >> 4);                 // fused row 0..383
      const int cc = (tid & 15) * 8;
      ushort8 xv = *(const ushort8*)&inpb[(size_t)src * WH + (size_t)rl * NH + h0 + cc];
      ushort8 pv = *(const ushort8*)&peb[r * NH + h0 + cc];
      bf16x8 o;
      #pragma unroll
      for (int j = 0; j < 8; ++j) o[j] = (__bf16)(b2f(xv[j]) + b2f(pv[j]));
      *reinterpret_cast<bf16x8*>(&Xs[r * XS2_STRIDE + cc]) = o;
    }
    __syncthreads();
    __builtin_amdgcn_s_setprio(1);
    #pragma unroll
    for (int ks = 0; ks < 128; ks += 32) {
      short8 a[4];
      #pragma unroll
      for (int qs = 0; qs < 4; ++qs)
        a[qs] = *reinterpret_cast<const short8*>(
            &Xs[(qh * 64 + qs * 16 + lrow) * XS2_STRIDE + ks + lhi * 8]);
      #pragma unroll
      for (int kf = 0; kf < 3; ++kf) {
        short8 b = *reinterpret_cast<const short8*>(
            &Xs[(kq * 48 + kf * 16 + lrow) * XS2_STRIDE + ks + lhi * 8]);
        #pragma unroll
        for (int qs = 0; qs < 4; ++qs)
          acc[qs][kf] = __builtin_amdgcn_mfma_f32_16x16x32_bf16(a[qs], b, acc[qs][kf], 0, 0, 0);
      }
    }
    __builtin_amdgcn_s_setprio(0);
    __syncthreads();
  }

  // ============ softmax (128 rows; k split across 8 kq-slices; red[128][8] reused) ============
  const float scale = 0.03608439182435161f;  // 1/sqrt(768)
  float mx[4][4];
  #pragma unroll
  for (int qs = 0; qs < 4; ++qs)
    #pragma unroll
    for (int r = 0; r < 4; ++r) {
      float m = fmaxf(fmaxf(acc[qs][0][r], acc[qs][1][r]), acc[qs][2][r]);
      #pragma unroll
      for (int d = 1; d < 16; d <<= 1) m = fmaxf(m, __shfl_xor(m, d, 64));
      mx[qs][r] = m;
    }
  if (lrow == 0) {
    #pragma unroll
    for (int qs = 0; qs < 4; ++qs)
      #pragma unroll
      for (int r = 0; r < 4; ++r)
        red[(qh * 64 + qs * 16 + lhi * 4 + r) * 8 + kq] = mx[qs][r];
  }
  __syncthreads();
  float sm[4][4];
  #pragma unroll
  for (int qs = 0; qs < 4; ++qs)
    #pragma unroll
    for (int r = 0; r < 4; ++r) {
      const int row = qh * 64 + qs * 16 + lhi * 4 + r;
      float4 m0 = *(const float4*)&red[row * 8];
      float4 m1 = *(const float4*)&red[row * 8 + 4];
      mx[qs][r] = fmaxf(fmaxf(fmaxf(m0.x, m0.y), fmaxf(m0.z, m0.w)),
                        fmaxf(fmaxf(m1.x, m1.y), fmaxf(m1.z, m1.w)));
      sm[qs][r] = 0.f;
    }
  #pragma unroll
  for (int qs = 0; qs < 4; ++qs)
    #pragma unroll
    for (int kf = 0; kf < 3; ++kf)
      #pragma unroll
      for (int r = 0; r < 4; ++r) {
        float p = __expf((acc[qs][kf][r] - mx[qs][r]) * scale);
        acc[qs][kf][r] = p;
        sm[qs][r] += p;
      }
  #pragma unroll
  for (int qs = 0; qs < 4; ++qs)
    #pragma unroll
    for (int r = 0; r < 4; ++r) {
      #pragma unroll
      for (int d = 1; d < 16; d <<= 1) sm[qs][r] += __shfl_xor(sm[qs][r], d, 64);
    }
  __syncthreads();    // all max-reads done; red reusable for sums
  if (lrow == 0) {
    #pragma unroll
    for (int qs = 0; qs < 4; ++qs)
      #pragma unroll
      for (int r = 0; r < 4; ++r)
        red[(qh * 64 + qs * 16 + lhi * 4 + r) * 8 + kq] = sm[qs][r];
  }
  __syncthreads();
  #pragma unroll
  for (int qs = 0; qs < 4; ++qs)
    #pragma unroll
    for (int r = 0; r < 4; ++r) {
      const int row = qh * 64 + qs * 16 + lhi * 4 + r;
      float4 s0 = *(const float4*)&red[row * 8];
      float4 s1 = *(const float4*)&red[row * 8 + 4];
      sm[qs][r] = 1.0f / ((s0.x + s0.y) + (s0.z + s0.w) + (s1.x + s1.y) + (s1.z + s1.w));
    }
  // write normalized P (bf16) -> Ps[128][392], byte-XOR ((row>>3)&7)<<4 (r8-proven)
  #pragma unroll
  for (int qs = 0; qs < 4; ++qs)
    #pragma unroll
    for (int kf = 0; kf < 3; ++kf)
      #pragma unroll
      for (int r = 0; r < 4; ++r) {
        const int row = qh * 64 + qs * 16 + lhi * 4 + r;
        const int col = kq * 48 + kf * 16 + lrow;
        *(unsigned short*)((char*)Ps + (((row * PS_STRIDE + col) * 2) ^ (((row >> 3) & 7) << 4))) =
            bfc(acc[qs][kf][r] * sm[qs][r]);
      }
  __syncthreads();

  // ============ PV: 12 tiles of 64 h-cols; wave (qb,hsub) = 16q x 32h per tile ============
  const int qb = wid & 7, hsub = wid >> 3;
  short8 pa[12];                            // 48 regs, register-safe (r9-proven footprint)
  #pragma unroll
  for (int m0 = 0; m0 < 12; ++m0) {
    const int row = qb * 16 + lrow;
    pa[m0] = *reinterpret_cast<const short8*>(
        (const char*)Ps + (((row * PS_STRIDE + m0 * 32 + lhi * 8) * 2) ^ (((row >> 3) & 7) << 4)));
  }
  const int ml = tid >> 3, c8 = (tid & 7) * 8;
  const int q_out = qb * 16 + lhi * 4;

  for (int t4 = 0; t4 < 12; ++t4) {
    const int h0 = t4 * 64;
    #pragma unroll
    for (int it = 0; it < 3; ++it) {        // 128 rows x 8 col-groups per it
      const int src = (it == 0) ? i0 : (it == 1 ? i1 : i2);
      const int m = it * 128 + ml;          // fused row 0..383
      ushort8 xv = *(const ushort8*)&inpb[(size_t)src * WH + (size_t)ml * NH + h0 + c8];
      ushort8 pv = *(const ushort8*)&peb[m * NH + h0 + c8];
      #pragma unroll
      for (int j = 0; j < 8; ++j) {
        const int vr = c8 + j;              // 0..63
        VT[((vr * PS_STRIDE) + m) ^ (((vr >> 3) & 7) << 3)] = bfc(b2f(xv[j]) + b2f(pv[j]));
      }
    }
    __syncthreads();
    __builtin_amdgcn_s_setprio(1);
    f32x4 o0 = fz, o1 = fz;
    const int vr0 = hsub * 32 + lrow, vr1 = vr0 + 16;
    const int sw0 = ((vr0 >> 3) & 7) << 4, sw1 = ((vr1 >> 3) & 7) << 4;
    #pragma unroll
    for (int mm = 0; mm < 12; ++mm) {
      const int moff = (mm * 32 + lhi * 8) * 2;
      short8 b0 = *reinterpret_cast<const short8*>((const char*)VT + ((vr0 * PS_STRIDE * 2 + moff) ^ sw0));
      short8 b1 = *reinterpret_cast<const short8*>((const char*)VT + ((vr1 * PS_STRIDE * 2 + moff) ^ sw1));
      o0 = __builtin_amdgcn_mfma_f32_16x16x32_bf16(pa[mm], b0, o0, 0, 0, 0);
      o1 = __builtin_amdgcn_mfma_f32_16x16x32_bf16(pa[mm], b1, o1, 0, 0, 0);
    }
    __builtin_amdgcn_s_setprio(0);
    float* ob = out + (size_t)s * (OUTROWS * NH) + h0 + hsub * 32 + lrow;
    #pragma unroll
    for (int hf = 0; hf < 2; ++hf) {
      f32x4 o = hf == 0 ? o0 : o1;
      #pragma unroll
      for (int r = 0; r < 4; ++r) {
        const int q = q_out + r;
        if (q < OUTROWS) ob[(size_t)q * NH + hf * 16] = o[r];
      }
    }
    __syncthreads();
  }
}

// ---------------- launch ----------------
extern "C" void kernel_launch(void* const* d_in, const int* in_sizes, int n_in,
                              void* d_out, int out_size, void* d_ws, size_t ws_size,
                              hipStream_t stream) {
  (void)in_sizes; (void)n_in; (void)out_size; (void)ws_size;
  const float* inp = (const float*)d_in[0];
  float* out = (float*)d_out;
  char* ws = (char*)d_ws;

  unsigned short* peb = (unsigned short*)ws;                     // 589824 B
  int* idxw           = (int*)(ws + 589824);                     // 3072 B
  unsigned short* inpb= (unsigned short*)(ws + 592896);          // 50331648 B

  hipLaunchKernelGGL(k_pre, dim3(256 + 288 + 3072), dim3(1024), 0, stream,
                     inp, idxw, peb, inpb);

  hipFuncSetAttribute((const void*)k_attn,
                      hipFuncAttributeMaxDynamicSharedMemorySize, SMEM_TOTAL);
  hipLaunchKernelGGL(k_attn, dim3(256), dim3(1024), SMEM_TOTAL, stream,
                     inpb, peb, idxw, out);
}